// Round 10
// baseline (12247.058 us; speedup 1.0000x reference)
//
#include <hip/hip_runtime.h>

// LSTM B=1024, T=256, H=256, fp32-accurate via bf16x2-split (3-term) MFMA. v10.
// Grid 256 = 32 rowgroups (32 rows) x 8 colgroups (32 hcols) -- 1 block/CU
// (v9's grid-512 required 2-block/CU co-residency and deadlocked; v4-v8 all
// completed at 1/CU). Block 512 thr = 8 waves; wave = full K=256 for its 16
// gatecols (16x16x32 MFMA; A row=lane&15, k=ks*32+(lane>>4)*8+e; D col=lane&15,
// row=(lane>>4)*4+reg). Rows split into halves X=rows0..15, Y=rows16..31,
// pipelined: while one half's exchange flags/loads fly, the other computes.
//
// DEADLOCK-FREEDOM (slot order X(t) < Y(t) < X(t+1) < ...): every blocking
// spin is placed AFTER the release of the current slot and waits only on a
// strictly EARLIER slot (Y(t)-spin after releaseX(t) waits partners'
// releaseY(t-1); X(t+1)-spin after releaseY(t) waits partners' releaseX(t)).
// By induction every release at slot s depends only on releases < s: acyclic.
// The optimistic early-fetch never blocks (single flag check, load only if
// already released). RACE-FREEDOM: all reads of buffer cols published at slot
// s are drained by the vmcnt(0) preceding our own slot-s' release, and any
// overwrite of those cols (slot s+2) transitively requires all blocks' slot-
// s+1 releases, which require all staged reads complete.
//
// Weights: 8 ksteps x 2 bf16 splits x short8 = 64 VGPR/lane, MFMA B-operands.
// 3 split terms in 3 INDEPENDENT acc chains (aA=a1*b1, aB=a2*b1, aC=a1*b2).
// h exchanged as packed u32 (bf16 hi+lo) agent-scope coherent; per-wave flag
// release (8 adds per half-slot); own colgroup slice via hown LDS.

#define Bsz   1024
#define Tt    256
#define Hh    256
#define NCLS  10
#define RGR   32
#define NRG   32
#define NCG   8
#define NTHR  512
#define HSZ   ((size_t)Bsz * Hh)      // u32 elems per hpack buffer

typedef float f32x4 __attribute__((ext_vector_type(4)));
typedef short s16x8 __attribute__((ext_vector_type(8)));
typedef unsigned long long u64;
typedef unsigned int u32;

// LDS layout (bytes): plane1 8K | plane2 8K | hown 32 x 44 u32
#define PL1    0
#define POFF   8192
#define HOWNB  16384
#define HSTR   44
#define SMEMB  (16384 + 32 * HSTR * 4)   // 22016 B

__device__ __forceinline__ unsigned short f2bf(float f) {   // RNE f32->bf16
    u32 u = __builtin_bit_cast(u32, f);
    return (unsigned short)((u + 0x7FFFu + ((u >> 16) & 1u)) >> 16);
}
__device__ __forceinline__ float bf2f(unsigned short b) {
    u32 u = ((u32)b) << 16;
    return __builtin_bit_cast(float, u);
}
template<int CTRL>
__device__ __forceinline__ float quadf(float v) {           // quad_perm bcast
    return __builtin_bit_cast(float,
        __builtin_amdgcn_update_dpp(0, __builtin_bit_cast(int, v),
                                    CTRL, 0xF, 0xF, true));
}
__device__ __forceinline__ float fast_tanh(float v) {
    const float e = __expf(-2.0f * fabsf(v));
    const float t = (1.0f - e) * __builtin_amdgcn_rcpf(1.0f + e);
    return copysignf(t, v);
}
__device__ __forceinline__ u64 coh_load64(const u64* p) {
    return __hip_atomic_load((u64*)p, __ATOMIC_RELAXED, __HIP_MEMORY_SCOPE_AGENT);
}
__device__ __forceinline__ unsigned coh_load32(const unsigned* p) {
    return __hip_atomic_load((unsigned*)p, __ATOMIC_RELAXED, __HIP_MEMORY_SCOPE_AGENT);
}
__device__ __forceinline__ void coh_store32(u32* p, u32 v) {
    __hip_atomic_store(p, v, __ATOMIC_RELAXED, __HIP_MEMORY_SCOPE_AGENT);
}

extern "C" __global__ void __launch_bounds__(NTHR, 2)
lstm_v10(const float* __restrict__ x,
         const float* __restrict__ W_gx, const float* __restrict__ W_gh, const float* __restrict__ b_g,
         const float* __restrict__ W_ix, const float* __restrict__ W_ih, const float* __restrict__ b_i,
         const float* __restrict__ W_fx, const float* __restrict__ W_fh, const float* __restrict__ b_f,
         const float* __restrict__ W_ox, const float* __restrict__ W_oh, const float* __restrict__ b_o,
         const float* __restrict__ W_ph, const float* __restrict__ b_p,
         float* __restrict__ out, u32* __restrict__ hpack, unsigned* __restrict__ fcnt)
{
    __shared__ __align__(16) char smem[SMEMB];
    u32* hown = (u32*)(smem + HOWNB);

    const int tid  = threadIdx.x;
    const int lane = tid & 63;
    const int wv   = tid >> 6;            // wave id; also the colgroup it stages
    const int rg   = blockIdx.x & 31;     // partner blocks share rg
    const int cg   = blockIdx.x >> 5;
    const int r0   = rg * RGR;

    const int gate   = lane & 3;          // gc = hcol*4 + gate
    const int hcol_l = wv * 4 + ((lane & 15) >> 2);
    const int hcol_g = cg * 32 + hcol_l;
    const int krow   = lane >> 4;

    // ---- B-frags: 8 ksteps x 2 splits = 64 VGPR/lane ----
    const float* __restrict__ Wg =
        (gate == 0) ? W_gh : (gate == 1) ? W_ih : (gate == 2) ? W_fh : W_oh;
    s16x8 bw1[8], bw2[8];
    #pragma unroll
    for (int ks = 0; ks < 8; ++ks) {
        s16x8 v1, v2;
        #pragma unroll
        for (int e = 0; e < 8; ++e) {
            const float w = Wg[(size_t)(ks * 32 + krow * 8 + e) * Hh + hcol_g];
            const unsigned short c1 = f2bf(w);
            const unsigned short c2 = f2bf(w - bf2f(c1));
            v1[e] = (short)c1; v2[e] = (short)c2;
        }
        bw1[ks] = v1; bw2[ks] = v2;
    }

    // reference bias swap preserved: f-gate uses b_o, o-gate uses b_f
    const float wx = ((gate == 0) ? W_gx : (gate == 1) ? W_ix : (gate == 2) ? W_fx : W_ox)[hcol_g];
    const float bb = ((gate == 0) ? b_g  : (gate == 1) ? b_i  : (gate == 2) ? b_o  : b_f )[hcol_g];
    float c0v[4], c1v[4];
    #pragma unroll
    for (int r = 0; r < 4; ++r) { c0v[r] = 0.0f; c1v[r] = 0.0f; }

    unsigned*       fb = fcnt + (rg * NCG + cg) * 2;   // own flags [half]
    const unsigned* fw = fcnt + (rg * NCG + wv) * 2;   // staged colgroup's flags

    for (int i = tid; i < 32 * HSTR; i += NTHR) hown[i] = 0u;
    __syncthreads();

    const int srow = lane & 15;
    const int sg8  = lane >> 4;

    // load my 32-col slice of a half (no spin here; caller guards readiness)
    auto load_slice = [&](const u32* hbuf_cur, int half, u32* v) {
        if (wv != cg) {
            const u64* src = (const u64*)(hbuf_cur +
                (size_t)(r0 + half * 16 + srow) * Hh + wv * 32 + sg8 * 8);
            #pragma unroll
            for (int i = 0; i < 4; ++i) {
                const u64 q = coh_load64(src + i);
                v[2 * i] = (u32)q; v[2 * i + 1] = (u32)(q >> 32);
            }
        } else {
            const u32* hp = hown + (half * 16 + srow) * HSTR + sg8 * 8;
            const uint4 q0 = *(const uint4*)hp;
            const uint4 q1 = *(const uint4*)(hp + 4);
            v[0] = q0.x; v[1] = q0.y; v[2] = q0.z; v[3] = q0.w;
            v[4] = q1.x; v[5] = q1.y; v[6] = q1.z; v[7] = q1.w;
        }
    };

    auto compute_half = [&](const u32* v, f32x4& accOut) {
        s16x8 a1s, a2s;
        #pragma unroll
        for (int e = 0; e < 8; ++e) {
            a1s[e] = (short)(v[e] & 0xffffu);
            a2s[e] = (short)(v[e] >> 16);
        }
        *(s16x8*)(smem + PL1 + wv * 1024 + lane * 16)        = a1s;
        *(s16x8*)(smem + PL1 + POFF + wv * 1024 + lane * 16) = a2s;
        __syncthreads();                           // planes ready
        f32x4 aA = {0.f,0.f,0.f,0.f}, aB = {0.f,0.f,0.f,0.f}, aC = {0.f,0.f,0.f,0.f};
        #pragma unroll
        for (int ks = 0; ks < 8; ++ks) {
            const char* ab = smem + PL1 + ks * 1024 + lane * 16;
            const s16x8 a1 = *(const s16x8*)ab;
            const s16x8 a2 = *(const s16x8*)(ab + POFF);
            aA = __builtin_amdgcn_mfma_f32_16x16x32_bf16(a1, bw1[ks], aA, 0, 0, 0);
            aB = __builtin_amdgcn_mfma_f32_16x16x32_bf16(a2, bw1[ks], aB, 0, 0, 0);
            aC = __builtin_amdgcn_mfma_f32_16x16x32_bf16(a1, bw2[ks], aC, 0, 0, 0);
        }
        accOut = aA + aB + aC;
    };

    auto phase_b = [&](const f32x4& acc, const float* xv, float* cst, int half, u32* hn) {
        #pragma unroll
        for (int r = 0; r < 4; ++r) {
            const int row = half * 16 + krow * 4 + r;
            const float pre = acc[r] + fmaf(xv[r], wx, bb);
            const float vin = (gate == 0) ? 2.0f * pre : pre;
            const float e   = __expf(-fabsf(vin));
            const float rc  = __builtin_amdgcn_rcpf(1.0f + e);
            const float sig = (vin >= 0.0f) ? rc : 1.0f - rc;
            const float th  = copysignf((1.0f - e) * rc, pre);
            const float act = (gate == 0) ? th : sig;
            const float gv = quadf<0x00>(act);
            const float iv = quadf<0x55>(act);
            const float fv = quadf<0xAA>(act);
            const float ov = quadf<0xFF>(act);
            cst[r] = fmaf(gv, iv, cst[r] * fv);
            const float hv = fast_tanh(cst[r]) * ov;
            if (gate == 0) {
                const unsigned short h1 = f2bf(hv);
                const unsigned short h2 = f2bf(hv - bf2f(h1));
                const u32 packed = (u32)h1 | ((u32)h2 << 16);
                coh_store32(hn + (size_t)(r0 + row) * Hh + hcol_g, packed);
                hown[row * HSTR + hcol_l] = packed;
            }
        }
    };

    u32 vX[8], vY[8];
    load_slice(hpack, 0, vX);                     // X(0): buf0 = zeros (memset)

    for (int t = 0; t < Tt; ++t) {
        const u32* hcur = hpack + ((t & 1) ? HSZ : 0);
        u32*       hnxt = hpack + ((t & 1) ? 0 : HSZ);

        float xvX[4], xvY[4];
        #pragma unroll
        for (int r = 0; r < 4; ++r)
            xvX[r] = x[(size_t)(r0 + krow * 4 + r) * Tt + t];

        // ================= half X =================
        f32x4 accX; compute_half(vX, accX);

        #pragma unroll
        for (int r = 0; r < 4; ++r)
            xvY[r] = x[(size_t)(r0 + 16 + krow * 4 + r) * Tt + t];

        // optimistic early fetch of Y(t): only if already published
        bool yDone = (wv == cg) || (coh_load32(fw + 1) >= 8u * (unsigned)t);
        if (yDone) load_slice(hcur, 1, vY);

        phase_b(accX, xvX, c0v, 0, hnxt);
        asm volatile("s_waitcnt vmcnt(0)" ::: "memory");   // h stores + vY reads drained
        if (lane == 0)
            __hip_atomic_fetch_add(fb + 0, 1u, __ATOMIC_RELEASE, __HIP_MEMORY_SCOPE_AGENT);
        if (!yDone) {                              // slow path: waits slot Y(t-1) only
            const unsigned thr = 8u * (unsigned)t;
            while (coh_load32(fw + 1) < thr) __builtin_amdgcn_s_sleep(1);
            load_slice(hcur, 1, vY);
        }
        __syncthreads();                           // MFMA-X plane reads done

        // ================= half Y =================
        f32x4 accY; compute_half(vY, accY);

        bool xDone = false;
        if (t + 1 < Tt) {                          // optimistic early fetch of X(t+1)
            xDone = (wv == cg) || (coh_load32(fw + 0) >= 8u * (unsigned)(t + 1));
            if (xDone) load_slice(hnxt, 0, vX);    // h(t+1) lives in hnxt
        }

        phase_b(accY, xvY, c1v, 1, hnxt);
        asm volatile("s_waitcnt vmcnt(0)" ::: "memory");
        if (lane == 0)
            __hip_atomic_fetch_add(fb + 1, 1u, __ATOMIC_RELEASE, __HIP_MEMORY_SCOPE_AGENT);
        if (t + 1 < Tt && !xDone) {                // waits slot X(t) only
            const unsigned thr = 8u * (unsigned)(t + 1);
            while (coh_load32(fw + 0) < thr) __builtin_amdgcn_s_sleep(1);
            load_slice(hnxt, 0, vX);
        }
        __syncthreads();                           // MFMA-Y plane reads done
    }

    // ---- classifier (cg==0): out = h_T @ W_ph + b_p (h_T = h(256) in buf0) ----
    if (cg == 0) {
        const unsigned done = 8u * (unsigned)Tt;
        for (int c = 0; c < NCG; ++c) {
            const unsigned* f = fcnt + (rg * NCG + c) * 2;
            while (coh_load32(f + 0) < done) __builtin_amdgcn_s_sleep(1);
            while (coh_load32(f + 1) < done) __builtin_amdgcn_s_sleep(1);
        }
        u32* tile = (u32*)smem;                    // 16 x 256 u32 = 16 KB chunk
        for (int hf = 0; hf < 2; ++hf) {
            const u64* src = (const u64*)(hpack + (size_t)(r0 + hf * 16) * Hh);
            for (int i = tid; i < 16 * 128; i += NTHR) {
                const u64 q = coh_load64(src + i);
                tile[2 * i] = (u32)q; tile[2 * i + 1] = (u32)(q >> 32);
            }
            __syncthreads();
            for (int idx = tid; idx < 16 * NCLS; idx += NTHR) {
                const int row = idx / NCLS;
                const int cc  = idx - row * NCLS;
                float a = b_p[cc];
                for (int k = 0; k < Hh; ++k) {
                    const u32 p = tile[row * Hh + k];
                    a = fmaf(bf2f((unsigned short)p) + bf2f((unsigned short)(p >> 16)),
                             W_ph[k * NCLS + cc], a);
                }
                out[(size_t)(r0 + hf * 16 + row) * NCLS + cc] = a;
            }
            __syncthreads();
        }
    }
}

extern "C" void kernel_launch(void* const* d_in, const int* in_sizes, int n_in,
                              void* d_out, int out_size, void* d_ws, size_t ws_size,
                              hipStream_t stream) {
    const float* x    = (const float*)d_in[0];
    const float* W_gx = (const float*)d_in[1];
    const float* W_gh = (const float*)d_in[2];
    const float* b_g  = (const float*)d_in[3];
    const float* W_ix = (const float*)d_in[4];
    const float* W_ih = (const float*)d_in[5];
    const float* b_i  = (const float*)d_in[6];
    const float* W_fx = (const float*)d_in[7];
    const float* W_fh = (const float*)d_in[8];
    const float* b_f  = (const float*)d_in[9];
    const float* W_ox = (const float*)d_in[10];
    const float* W_oh = (const float*)d_in[11];
    const float* b_o  = (const float*)d_in[12];
    const float* W_ph = (const float*)d_in[13];
    const float* b_p  = (const float*)d_in[14];
    float* out = (float*)d_out;

    u32*      hpack = (u32*)d_ws;                        // 2 x 1 MB ping-pong
    unsigned* fcnt  = (unsigned*)((char*)d_ws + 2 * HSZ * sizeof(u32));
    const size_t clear_bytes = 2 * HSZ * sizeof(u32) + NRG * NCG * 2 * sizeof(unsigned);

    hipMemsetAsync(d_ws, 0, clear_bytes, stream);        // h0 = 0 + flags = 0

    lstm_v10<<<dim3(NRG * NCG), dim3(NTHR), 0, stream>>>(
        x, W_gx, W_gh, b_g, W_ix, W_ih, b_i, W_fx, W_fh, b_f,
        W_ox, W_oh, b_o, W_ph, b_p, out, hpack, fcnt);
}

// Round 11
// 1940.093 us; speedup vs baseline: 6.3126x; 6.3126x over previous
//
#include <hip/hip_runtime.h>

// LSTM B=1024, T=256, H=256, fp32-accurate via bf16x2-split (3-term) MFMA. v11.
// Grid 256 = 64 rowgroups (16 rows) x 4 colgroups (64 hcols) -- 1 block/CU.
// bid = cg*64+rg -> a rowgroup's 4 partner blocks share an XCD (bid mod 8 equal).
// Block 1024 thr = 16 waves (4/SIMD for latency hiding). Wave w = full K=256
// for 16 gatecols (4 hcols x 4 gates), 16x16x32 MFMA:
//   A[row=lane&15, k=ks*32+(lane>>4)*8+e], D[col=lane&15, row=(lane>>4)*4+reg].
// Weights: 8 ksteps x 2 bf16 splits x short8 = 64 VGPR/lane (proven resident).
// LDS planes in frag order with XOR swizzle on byte bits 4..6 (f(ks,krow)) ->
// staging ds_writes AND frag ds_reads both conflict-free.
// Per step: [stage: wave (s=wv&3,q=wv>>2) loads 4 rows x 16 u32 of slice s
// (s==cg: from hown LDS), splits to 2 planes] -> sync -> [24 MFMA, 3 indep
// chains] -> [phase B in-reg: activations, quad_perm, c/h update, coherent
// packed-bf16x2 h store] -> vmcnt(0) -> sync -> tid0 release-store flag=t+1.
// 3 foreign flag spins per step (before compute, on step t-1's releases) ->
// acyclic -> deadlock-free. 2 barriers/step, 1 flag store, no RMW.

#define Bsz   1024
#define Tt    256
#define Hh    256
#define NCLS  10
#define RGR   16
#define NRG   64
#define NCG   4
#define NTHR  1024
#define HSZ   ((size_t)Bsz * Hh)      // u32 elems per hpack buffer

typedef float f32x4 __attribute__((ext_vector_type(4)));
typedef short s16x8 __attribute__((ext_vector_type(8)));
typedef unsigned int u32;
typedef u32  u32x2 __attribute__((ext_vector_type(2)));
typedef unsigned long long u64;

// LDS: plane1 8K | plane2 8K | hown 16 x 68 u32
#define PL1    0
#define PL2    8192
#define HOWNB  16384
#define HSTR   68
#define SMEMB  (16384 + 16 * HSTR * 4)

__device__ __forceinline__ unsigned short f2bf(float f) {   // RNE f32->bf16
    u32 u = __builtin_bit_cast(u32, f);
    return (unsigned short)((u + 0x7FFFu + ((u >> 16) & 1u)) >> 16);
}
__device__ __forceinline__ float bf2f(unsigned short b) {
    u32 u = ((u32)b) << 16;
    return __builtin_bit_cast(float, u);
}
template<int CTRL>
__device__ __forceinline__ float quadf(float v) {
    return __builtin_bit_cast(float,
        __builtin_amdgcn_update_dpp(0, __builtin_bit_cast(int, v),
                                    CTRL, 0xF, 0xF, true));
}
__device__ __forceinline__ float fast_tanh(float v) {
    const float e = __expf(-2.0f * fabsf(v));
    const float t = (1.0f - e) * __builtin_amdgcn_rcpf(1.0f + e);
    return copysignf(t, v);
}
__device__ __forceinline__ u64 coh_load64(const u64* p) {
    return __hip_atomic_load((u64*)p, __ATOMIC_RELAXED, __HIP_MEMORY_SCOPE_AGENT);
}
__device__ __forceinline__ unsigned coh_load32(const unsigned* p) {
    return __hip_atomic_load((unsigned*)p, __ATOMIC_RELAXED, __HIP_MEMORY_SCOPE_AGENT);
}
__device__ __forceinline__ void coh_store32(u32* p, u32 v) {
    __hip_atomic_store(p, v, __ATOMIC_RELAXED, __HIP_MEMORY_SCOPE_AGENT);
}
__device__ __forceinline__ int swz(int ks, int krow) {      // byte-bit 4..6 XOR
    return ((krow & 1) << 6) | ((ks & 1) << 5) | ((krow >> 1) << 4);
}

extern "C" __global__ void __launch_bounds__(NTHR)
lstm_v11(const float* __restrict__ x,
         const float* __restrict__ W_gx, const float* __restrict__ W_gh, const float* __restrict__ b_g,
         const float* __restrict__ W_ix, const float* __restrict__ W_ih, const float* __restrict__ b_i,
         const float* __restrict__ W_fx, const float* __restrict__ W_fh, const float* __restrict__ b_f,
         const float* __restrict__ W_ox, const float* __restrict__ W_oh, const float* __restrict__ b_o,
         const float* __restrict__ W_ph, const float* __restrict__ b_p,
         float* __restrict__ out, u32* __restrict__ hpack, unsigned* __restrict__ fcnt)
{
    __shared__ __align__(16) char smem[SMEMB];
    u32* hown = (u32*)(smem + HOWNB);

    const int tid  = threadIdx.x;
    const int lane = tid & 63;
    const int wv   = tid >> 6;            // 0..15
    const int rg   = blockIdx.x & 63;
    const int cg   = blockIdx.x >> 6;     // 0..3
    const int r0   = rg * RGR;

    const int gate   = lane & 3;
    const int hcol_l = wv * 4 + ((lane & 15) >> 2);    // 0..63
    const int hcol_g = cg * 64 + hcol_l;
    const int krow   = lane >> 4;                      // 0..3

    // ---- weights: 8 ksteps x 2 splits = 64 VGPR/lane ----
    const float* __restrict__ Wg =
        (gate == 0) ? W_gh : (gate == 1) ? W_ih : (gate == 2) ? W_fh : W_oh;
    s16x8 bw1[8], bw2[8];
    #pragma unroll
    for (int ks = 0; ks < 8; ++ks) {
        s16x8 v1, v2;
        #pragma unroll
        for (int e = 0; e < 8; ++e) {
            const float w = Wg[(size_t)(ks * 32 + krow * 8 + e) * Hh + hcol_g];
            const unsigned short c1 = f2bf(w);
            const unsigned short c2 = f2bf(w - bf2f(c1));
            v1[e] = (short)c1; v2[e] = (short)c2;
        }
        bw1[ks] = v1; bw2[ks] = v2;
    }

    // reference bias swap preserved: f-gate uses b_o, o-gate uses b_f
    const float wx = ((gate == 0) ? W_gx : (gate == 1) ? W_ix : (gate == 2) ? W_fx : W_ox)[hcol_g];
    const float bb = ((gate == 0) ? b_g  : (gate == 1) ? b_i  : (gate == 2) ? b_o  : b_f )[hcol_g];
    float c_st[4];
    #pragma unroll
    for (int r = 0; r < 4; ++r) c_st[r] = 0.0f;

    // ---- staging role: slice s (a colgroup), quarter q (4 rows) ----
    const int s    = wv & 3;
    const int q    = wv >> 2;
    const int srow = q * 4 + krow;                 // 0..15
    const int sc4  = (lane & 15) * 4;              // u32 col in 64-col slice
    const int kg   = s * 64 + sc4;                 // global k of v[0]
    const int sks  = kg >> 5;
    const int skr  = (kg >> 3) & 3;
    const int se0  = kg & 7;                       // 0 or 4
    const int swb  = (sks * 1024 + (skr * 16 + srow) * 16 + se0 * 2) ^ swz(sks, skr);

    unsigned* fbase = fcnt + rg * NCG;

    for (int i = tid; i < 16 * HSTR; i += NTHR) hown[i] = 0u;
    __syncthreads();

    for (int t = 0; t < Tt; ++t) {
        const u32* hcur = hpack + ((t & 1) ? HSZ : 0);
        u32*       hnxt = hpack + ((t & 1) ? 0 : HSZ);

        // x_t for phase-B rows (early, cached broadcast)
        float xv[4];
        #pragma unroll
        for (int r = 0; r < 4; ++r)
            xv[r] = x[(size_t)(r0 + krow * 4 + r) * Tt + t];

        // ---- stage slice s: 4 u32 per lane ----
        u32 v0, v1, v2, v3;
        if (s != cg) {
            if (t > 0)
                while (coh_load32(fbase + s) < (unsigned)t) __builtin_amdgcn_s_sleep(1);
            const u64* src = (const u64*)(hcur + (size_t)(r0 + srow) * Hh + s * 64 + sc4);
            const u64 q0 = coh_load64(src);
            const u64 q1 = coh_load64(src + 1);
            v0 = (u32)q0; v1 = (u32)(q0 >> 32);
            v2 = (u32)q1; v3 = (u32)(q1 >> 32);
        } else {
            const uint4 qq = *(const uint4*)(hown + srow * HSTR + sc4);
            v0 = qq.x; v1 = qq.y; v2 = qq.z; v3 = qq.w;
        }
        {
            u32x2 lo, hi;
            lo[0] = (v0 & 0xffffu) | (v1 << 16);
            lo[1] = (v2 & 0xffffu) | (v3 << 16);
            hi[0] = (v0 >> 16) | (v1 & 0xffff0000u);
            hi[1] = (v2 >> 16) | (v3 & 0xffff0000u);
            *(u32x2*)(smem + PL1 + swb) = lo;
            *(u32x2*)(smem + PL2 + swb) = hi;
        }
        __syncthreads();                           // planes = split(h(t))

        // ---- MFMA: 8 ksteps x 3 terms, 3 independent chains ----
        f32x4 aA = {0.f,0.f,0.f,0.f}, aB = {0.f,0.f,0.f,0.f}, aC = {0.f,0.f,0.f,0.f};
        #pragma unroll
        for (int ks = 0; ks < 8; ++ks) {
            const int off = (ks * 1024 + lane * 16) ^ swz(ks, krow);
            const s16x8 a1 = *(const s16x8*)(smem + PL1 + off);
            const s16x8 a2 = *(const s16x8*)(smem + PL2 + off);
            aA = __builtin_amdgcn_mfma_f32_16x16x32_bf16(a1, bw1[ks], aA, 0, 0, 0);
            aB = __builtin_amdgcn_mfma_f32_16x16x32_bf16(a2, bw1[ks], aB, 0, 0, 0);
            aC = __builtin_amdgcn_mfma_f32_16x16x32_bf16(a1, bw2[ks], aC, 0, 0, 0);
        }
        const f32x4 acc = aA + aB + aC;

        // ---- phase B: 4 states/lane, in-register ----
        #pragma unroll
        for (int r = 0; r < 4; ++r) {
            const int row = krow * 4 + r;
            const float pre = acc[r] + fmaf(xv[r], wx, bb);
            const float vin = (gate == 0) ? 2.0f * pre : pre;
            const float e   = __expf(-fabsf(vin));
            const float rc  = __builtin_amdgcn_rcpf(1.0f + e);
            const float sig = (vin >= 0.0f) ? rc : 1.0f - rc;
            const float th  = copysignf((1.0f - e) * rc, pre);
            const float act = (gate == 0) ? th : sig;
            const float gv = quadf<0x00>(act);
            const float iv = quadf<0x55>(act);
            const float fv = quadf<0xAA>(act);
            const float ov = quadf<0xFF>(act);
            c_st[r] = fmaf(gv, iv, c_st[r] * fv);
            const float hv = fast_tanh(c_st[r]) * ov;
            if (gate == 0) {
                const unsigned short h1 = f2bf(hv);
                const unsigned short h2 = f2bf(hv - bf2f(h1));
                const u32 packed = (u32)h1 | ((u32)h2 << 16);
                coh_store32(&hnxt[(size_t)(r0 + row) * Hh + hcol_g], packed);
                hown[row * HSTR + hcol_l] = packed;
            }
        }

        asm volatile("s_waitcnt vmcnt(0)" ::: "memory");   // h stores at L3
        __syncthreads();                                    // all waves drained
        if (tid == 0)
            __hip_atomic_store(fbase + cg, (unsigned)(t + 1),
                               __ATOMIC_RELEASE, __HIP_MEMORY_SCOPE_AGENT);
    }

    // ---- classifier (cg==0): out = h_T @ W_ph + b_p (h_T in buffer 0) ----
    if (cg == 0) {
        for (int c = 1; c < NCG; ++c)
            while (coh_load32(fbase + c) < (unsigned)Tt) __builtin_amdgcn_s_sleep(1);
        u32* tile = (u32*)smem;                    // [16][256] packed h_T
        const u64* src = (const u64*)(hpack + (size_t)r0 * Hh);
        for (int i = tid; i < 16 * 128; i += NTHR) {
            const u64 qv = coh_load64(src + i);
            tile[2 * i] = (u32)qv; tile[2 * i + 1] = (u32)(qv >> 32);
        }
        __syncthreads();
        for (int idx = tid; idx < RGR * NCLS; idx += NTHR) {
            const int row = idx / NCLS;
            const int cc  = idx - row * NCLS;
            float a = b_p[cc];
            for (int k = 0; k < Hh; ++k) {
                const u32 p = tile[row * Hh + k];
                a = fmaf(bf2f((unsigned short)p) + bf2f((unsigned short)(p >> 16)),
                         W_ph[k * NCLS + cc], a);
            }
            out[(size_t)(r0 + row) * NCLS + cc] = a;
        }
    }
}

extern "C" void kernel_launch(void* const* d_in, const int* in_sizes, int n_in,
                              void* d_out, int out_size, void* d_ws, size_t ws_size,
                              hipStream_t stream) {
    const float* x    = (const float*)d_in[0];
    const float* W_gx = (const float*)d_in[1];
    const float* W_gh = (const float*)d_in[2];
    const float* b_g  = (const float*)d_in[3];
    const float* W_ix = (const float*)d_in[4];
    const float* W_ih = (const float*)d_in[5];
    const float* b_i  = (const float*)d_in[6];
    const float* W_fx = (const float*)d_in[7];
    const float* W_fh = (const float*)d_in[8];
    const float* b_f  = (const float*)d_in[9];
    const float* W_ox = (const float*)d_in[10];
    const float* W_oh = (const float*)d_in[11];
    const float* b_o  = (const float*)d_in[12];
    const float* W_ph = (const float*)d_in[13];
    const float* b_p  = (const float*)d_in[14];
    float* out = (float*)d_out;

    u32*      hpack = (u32*)d_ws;                        // 2 x 1 MB ping-pong
    unsigned* fcnt  = (unsigned*)((char*)d_ws + 2 * HSZ * sizeof(u32));
    const size_t clear_bytes = 2 * HSZ * sizeof(u32) + NRG * NCG * sizeof(unsigned);

    hipMemsetAsync(d_ws, 0, clear_bytes, stream);        // h0 = 0 + flags = 0

    lstm_v11<<<dim3(NRG * NCG), dim3(NTHR), 0, stream>>>(
        x, W_gx, W_gh, b_g, W_ix, W_ih, b_i, W_fx, W_fh, b_f,
        W_ox, W_oh, b_o, W_ph, b_p, out, hpack, fcnt);
}

// Round 12
// 1933.066 us; speedup vs baseline: 6.3356x; 1.0036x over previous
//
#include <hip/hip_runtime.h>

// LSTM B=1024, T=256, H=256, fp32-accurate via bf16x2-split (3-term) MFMA. v12.
// == v11 with ONE change: __launch_bounds__(1024, 4) so the VGPR cap is 128
// and the 64-VGPR weight-fragment file stays register-resident (v11 compiled
// at VGPR=64 -> weights re-loaded from L2 every timestep; v8 proved frags
// stay resident when the cap permits).
//
// Grid 256 = 64 rowgroups (16 rows) x 4 colgroups (64 hcols) -- 1 block/CU.
// Block 1024 thr = 16 waves (4/SIMD). Wave w = full K=256 for 16 gatecols
// (4 hcols x 4 gates), 16x16x32 MFMA:
//   A[row=lane&15, k=ks*32+(lane>>4)*8+e], D[col=lane&15, row=(lane>>4)*4+reg].
// Weights: 8 ksteps x 2 bf16 splits x short8 = 64 VGPR/lane (B-operands).
// LDS planes in frag order, XOR swizzle on byte bits 4..6 -> writes <=2-way.
// Per step: [stage slice s=wv&3 (s==cg: from hown LDS; else spin flag>=t then
// coherent load)] -> sync -> [24 MFMA, 3 indep chains] -> [phase B in-reg:
// activations, quad_perm, c/h update, coherent packed-bf16x2 h store]
// -> vmcnt(0) -> sync -> tid0 release-store flag=t+1.
// Spins wait only on step t-1 releases -> acyclic -> deadlock-free @ 1 blk/CU.

#define Bsz   1024
#define Tt    256
#define Hh    256
#define NCLS  10
#define RGR   16
#define NRG   64
#define NCG   4
#define NTHR  1024
#define HSZ   ((size_t)Bsz * Hh)      // u32 elems per hpack buffer

typedef float f32x4 __attribute__((ext_vector_type(4)));
typedef short s16x8 __attribute__((ext_vector_type(8)));
typedef unsigned int u32;
typedef u32  u32x2 __attribute__((ext_vector_type(2)));
typedef unsigned long long u64;

// LDS: plane1 8K | plane2 8K | hown 16 x 68 u32
#define PL1    0
#define PL2    8192
#define HOWNB  16384
#define HSTR   68
#define SMEMB  (16384 + 16 * HSTR * 4)

__device__ __forceinline__ unsigned short f2bf(float f) {   // RNE f32->bf16
    u32 u = __builtin_bit_cast(u32, f);
    return (unsigned short)((u + 0x7FFFu + ((u >> 16) & 1u)) >> 16);
}
__device__ __forceinline__ float bf2f(unsigned short b) {
    u32 u = ((u32)b) << 16;
    return __builtin_bit_cast(float, u);
}
template<int CTRL>
__device__ __forceinline__ float quadf(float v) {
    return __builtin_bit_cast(float,
        __builtin_amdgcn_update_dpp(0, __builtin_bit_cast(int, v),
                                    CTRL, 0xF, 0xF, true));
}
__device__ __forceinline__ float fast_tanh(float v) {
    const float e = __expf(-2.0f * fabsf(v));
    const float t = (1.0f - e) * __builtin_amdgcn_rcpf(1.0f + e);
    return copysignf(t, v);
}
__device__ __forceinline__ u64 coh_load64(const u64* p) {
    return __hip_atomic_load((u64*)p, __ATOMIC_RELAXED, __HIP_MEMORY_SCOPE_AGENT);
}
__device__ __forceinline__ unsigned coh_load32(const unsigned* p) {
    return __hip_atomic_load((unsigned*)p, __ATOMIC_RELAXED, __HIP_MEMORY_SCOPE_AGENT);
}
__device__ __forceinline__ void coh_store32(u32* p, u32 v) {
    __hip_atomic_store(p, v, __ATOMIC_RELAXED, __HIP_MEMORY_SCOPE_AGENT);
}
__device__ __forceinline__ int swz(int ks, int krow) {      // byte-bit 4..6 XOR
    return ((krow & 1) << 6) | ((ks & 1) << 5) | ((krow >> 1) << 4);
}

extern "C" __global__ void __launch_bounds__(NTHR, 4)
lstm_v12(const float* __restrict__ x,
         const float* __restrict__ W_gx, const float* __restrict__ W_gh, const float* __restrict__ b_g,
         const float* __restrict__ W_ix, const float* __restrict__ W_ih, const float* __restrict__ b_i,
         const float* __restrict__ W_fx, const float* __restrict__ W_fh, const float* __restrict__ b_f,
         const float* __restrict__ W_ox, const float* __restrict__ W_oh, const float* __restrict__ b_o,
         const float* __restrict__ W_ph, const float* __restrict__ b_p,
         float* __restrict__ out, u32* __restrict__ hpack, unsigned* __restrict__ fcnt)
{
    __shared__ __align__(16) char smem[SMEMB];
    u32* hown = (u32*)(smem + HOWNB);

    const int tid  = threadIdx.x;
    const int lane = tid & 63;
    const int wv   = tid >> 6;            // 0..15
    const int rg   = blockIdx.x & 63;
    const int cg   = blockIdx.x >> 6;     // 0..3
    const int r0   = rg * RGR;

    const int gate   = lane & 3;
    const int hcol_l = wv * 4 + ((lane & 15) >> 2);    // 0..63
    const int hcol_g = cg * 64 + hcol_l;
    const int krow   = lane >> 4;                      // 0..3

    // ---- weights: 8 ksteps x 2 splits = 64 VGPR/lane ----
    const float* __restrict__ Wg =
        (gate == 0) ? W_gh : (gate == 1) ? W_ih : (gate == 2) ? W_fh : W_oh;
    s16x8 bw1[8], bw2[8];
    #pragma unroll
    for (int ks = 0; ks < 8; ++ks) {
        s16x8 v1, v2;
        #pragma unroll
        for (int e = 0; e < 8; ++e) {
            const float w = Wg[(size_t)(ks * 32 + krow * 8 + e) * Hh + hcol_g];
            const unsigned short c1 = f2bf(w);
            const unsigned short c2 = f2bf(w - bf2f(c1));
            v1[e] = (short)c1; v2[e] = (short)c2;
        }
        bw1[ks] = v1; bw2[ks] = v2;
    }

    // reference bias swap preserved: f-gate uses b_o, o-gate uses b_f
    const float wx = ((gate == 0) ? W_gx : (gate == 1) ? W_ix : (gate == 2) ? W_fx : W_ox)[hcol_g];
    const float bb = ((gate == 0) ? b_g  : (gate == 1) ? b_i  : (gate == 2) ? b_o  : b_f )[hcol_g];
    float c_st[4];
    #pragma unroll
    for (int r = 0; r < 4; ++r) c_st[r] = 0.0f;

    // ---- staging role: slice s (a colgroup), quarter q (4 rows) ----
    const int s    = wv & 3;
    const int q    = wv >> 2;
    const int srow = q * 4 + krow;                 // 0..15
    const int sc4  = (lane & 15) * 4;              // u32 col in 64-col slice
    const int kg   = s * 64 + sc4;                 // global k of v[0]
    const int sks  = kg >> 5;
    const int skr  = (kg >> 3) & 3;
    const int se0  = kg & 7;                       // 0 or 4
    const int swb  = (sks * 1024 + (skr * 16 + srow) * 16 + se0 * 2) ^ swz(sks, skr);

    unsigned* fbase = fcnt + rg * NCG;

    for (int i = tid; i < 16 * HSTR; i += NTHR) hown[i] = 0u;
    __syncthreads();

    for (int t = 0; t < Tt; ++t) {
        const u32* hcur = hpack + ((t & 1) ? HSZ : 0);
        u32*       hnxt = hpack + ((t & 1) ? 0 : HSZ);

        // x_t for phase-B rows (early, cached broadcast)
        float xv[4];
        #pragma unroll
        for (int r = 0; r < 4; ++r)
            xv[r] = x[(size_t)(r0 + krow * 4 + r) * Tt + t];

        // ---- stage slice s: 4 u32 per lane ----
        u32 v0, v1, v2, v3;
        if (s != cg) {
            if (t > 0)
                while (coh_load32(fbase + s) < (unsigned)t) __builtin_amdgcn_s_sleep(1);
            const u64* src = (const u64*)(hcur + (size_t)(r0 + srow) * Hh + s * 64 + sc4);
            const u64 q0 = coh_load64(src);
            const u64 q1 = coh_load64(src + 1);
            v0 = (u32)q0; v1 = (u32)(q0 >> 32);
            v2 = (u32)q1; v3 = (u32)(q1 >> 32);
        } else {
            const uint4 qq = *(const uint4*)(hown + srow * HSTR + sc4);
            v0 = qq.x; v1 = qq.y; v2 = qq.z; v3 = qq.w;
        }
        {
            u32x2 lo, hi;
            lo[0] = (v0 & 0xffffu) | (v1 << 16);
            lo[1] = (v2 & 0xffffu) | (v3 << 16);
            hi[0] = (v0 >> 16) | (v1 & 0xffff0000u);
            hi[1] = (v2 >> 16) | (v3 & 0xffff0000u);
            *(u32x2*)(smem + PL1 + swb) = lo;
            *(u32x2*)(smem + PL2 + swb) = hi;
        }
        __syncthreads();                           // planes = split(h(t))

        // ---- MFMA: 8 ksteps x 3 terms, 3 independent chains ----
        f32x4 aA = {0.f,0.f,0.f,0.f}, aB = {0.f,0.f,0.f,0.f}, aC = {0.f,0.f,0.f,0.f};
        #pragma unroll
        for (int ks = 0; ks < 8; ++ks) {
            const int off = (ks * 1024 + lane * 16) ^ swz(ks, krow);
            const s16x8 a1 = *(const s16x8*)(smem + PL1 + off);
            const s16x8 a2 = *(const s16x8*)(smem + PL2 + off);
            aA = __builtin_amdgcn_mfma_f32_16x16x32_bf16(a1, bw1[ks], aA, 0, 0, 0);
            aB = __builtin_amdgcn_mfma_f32_16x16x32_bf16(a2, bw1[ks], aB, 0, 0, 0);
            aC = __builtin_amdgcn_mfma_f32_16x16x32_bf16(a1, bw2[ks], aC, 0, 0, 0);
        }
        const f32x4 acc = aA + aB + aC;

        // ---- phase B: 4 states/lane, in-register ----
        #pragma unroll
        for (int r = 0; r < 4; ++r) {
            const int row = krow * 4 + r;
            const float pre = acc[r] + fmaf(xv[r], wx, bb);
            const float vin = (gate == 0) ? 2.0f * pre : pre;
            const float e   = __expf(-fabsf(vin));
            const float rc  = __builtin_amdgcn_rcpf(1.0f + e);
            const float sig = (vin >= 0.0f) ? rc : 1.0f - rc;
            const float th  = copysignf((1.0f - e) * rc, pre);
            const float act = (gate == 0) ? th : sig;
            const float gv = quadf<0x00>(act);
            const float iv = quadf<0x55>(act);
            const float fv = quadf<0xAA>(act);
            const float ov = quadf<0xFF>(act);
            c_st[r] = fmaf(gv, iv, c_st[r] * fv);
            const float hv = fast_tanh(c_st[r]) * ov;
            if (gate == 0) {
                const unsigned short h1 = f2bf(hv);
                const unsigned short h2 = f2bf(hv - bf2f(h1));
                const u32 packed = (u32)h1 | ((u32)h2 << 16);
                coh_store32(&hnxt[(size_t)(r0 + row) * Hh + hcol_g], packed);
                hown[row * HSTR + hcol_l] = packed;
            }
        }

        asm volatile("s_waitcnt vmcnt(0)" ::: "memory");   // h stores at L3
        __syncthreads();                                    // all waves drained
        if (tid == 0)
            __hip_atomic_store(fbase + cg, (unsigned)(t + 1),
                               __ATOMIC_RELEASE, __HIP_MEMORY_SCOPE_AGENT);
    }

    // ---- classifier (cg==0): out = h_T @ W_ph + b_p (h_T in buffer 0) ----
    if (cg == 0) {
        for (int c = 1; c < NCG; ++c)
            while (coh_load32(fbase + c) < (unsigned)Tt) __builtin_amdgcn_s_sleep(1);
        u32* tile = (u32*)smem;                    // [16][256] packed h_T
        const u64* src = (const u64*)(hpack + (size_t)r0 * Hh);
        for (int i = tid; i < 16 * 128; i += NTHR) {
            const u64 qv = coh_load64(src + i);
            tile[2 * i] = (u32)qv; tile[2 * i + 1] = (u32)(qv >> 32);
        }
        __syncthreads();
        for (int idx = tid; idx < RGR * NCLS; idx += NTHR) {
            const int row = idx / NCLS;
            const int cc  = idx - row * NCLS;
            float a = b_p[cc];
            for (int k = 0; k < Hh; ++k) {
                const u32 p = tile[row * Hh + k];
                a = fmaf(bf2f((unsigned short)p) + bf2f((unsigned short)(p >> 16)),
                         W_ph[k * NCLS + cc], a);
            }
            out[(size_t)(r0 + row) * NCLS + cc] = a;
        }
    }
}

extern "C" void kernel_launch(void* const* d_in, const int* in_sizes, int n_in,
                              void* d_out, int out_size, void* d_ws, size_t ws_size,
                              hipStream_t stream) {
    const float* x    = (const float*)d_in[0];
    const float* W_gx = (const float*)d_in[1];
    const float* W_gh = (const float*)d_in[2];
    const float* b_g  = (const float*)d_in[3];
    const float* W_ix = (const float*)d_in[4];
    const float* W_ih = (const float*)d_in[5];
    const float* b_i  = (const float*)d_in[6];
    const float* W_fx = (const float*)d_in[7];
    const float* W_fh = (const float*)d_in[8];
    const float* b_f  = (const float*)d_in[9];
    const float* W_ox = (const float*)d_in[10];
    const float* W_oh = (const float*)d_in[11];
    const float* b_o  = (const float*)d_in[12];
    const float* W_ph = (const float*)d_in[13];
    const float* b_p  = (const float*)d_in[14];
    float* out = (float*)d_out;

    u32*      hpack = (u32*)d_ws;                        // 2 x 1 MB ping-pong
    unsigned* fcnt  = (unsigned*)((char*)d_ws + 2 * HSZ * sizeof(u32));
    const size_t clear_bytes = 2 * HSZ * sizeof(u32) + NRG * NCG * sizeof(unsigned);

    hipMemsetAsync(d_ws, 0, clear_bytes, stream);        // h0 = 0 + flags = 0

    lstm_v12<<<dim3(NRG * NCG), dim3(NTHR), 0, stream>>>(
        x, W_gx, W_gh, b_g, W_ix, W_ih, b_i, W_fx, W_fh, b_f,
        W_ox, W_oh, b_o, W_ph, b_p, out, hpack, fcnt);
}

// Round 13
// 1927.606 us; speedup vs baseline: 6.3535x; 1.0028x over previous
//
#include <hip/hip_runtime.h>

// LSTM B=1024, T=256, H=256, fp32-accurate via bf16x2-split (3-term) MFMA. v13.
// == v12 + two changes targeting the weight-rematerialization tax (v12 PMC:
// VGPR=64 forced per-step re-load AND re-SPLIT of weights, ~450 VALU ops/lane
// /step = the dominant cost):
//  1. Weights are pre-split ONCE by a prep kernel into d_ws, laid out in
//     exact fragment order [cg][wv][ks][lane]x(16B); the main loop reads them
//     as coalesced dwordx4 with no VALU math -- cheap even if rematerialized.
//  2. amdgpu_waves_per_eu(4,4): occupancy is pinned at 4 waves/EU by the
//     resident 1024-thr block anyway; telling the allocator removes its
//     incentive to shrink below 128 VGPRs (launch_bounds min-waves was a null).
//
// Grid 256 = 64 rowgroups (16 rows) x 4 colgroups (64 hcols), 1 block/CU.
// Block 1024 thr = 16 waves. Wave = full K=256 for 16 gatecols, 16x16x32 MFMA.
// LDS planes frag-ordered + XOR swizzle. Exchange: agent-scope coherent
// packed-bf16x2 h, per-block monotonic flags, spins only on step t-1 -> acyclic.

#define Bsz   1024
#define Tt    256
#define Hh    256
#define NCLS  10
#define RGR   16
#define NRG   64
#define NCG   4
#define NTHR  1024
#define HSZ   ((size_t)Bsz * Hh)      // u32 elems per hpack buffer
#define WSPN  32768                   // s16x8 frags per split plane

typedef float f32x4 __attribute__((ext_vector_type(4)));
typedef short s16x8 __attribute__((ext_vector_type(8)));
typedef unsigned int u32;
typedef u32  u32x2 __attribute__((ext_vector_type(2)));
typedef unsigned long long u64;

// LDS: plane1 8K | plane2 8K | hown 16 x 68 u32
#define PL1    0
#define PL2    8192
#define HOWNB  16384
#define HSTR   68
#define SMEMB  (16384 + 16 * HSTR * 4)

__device__ __forceinline__ unsigned short f2bf(float f) {   // RNE f32->bf16
    u32 u = __builtin_bit_cast(u32, f);
    return (unsigned short)((u + 0x7FFFu + ((u >> 16) & 1u)) >> 16);
}
__device__ __forceinline__ float bf2f(unsigned short b) {
    u32 u = ((u32)b) << 16;
    return __builtin_bit_cast(float, u);
}
template<int CTRL>
__device__ __forceinline__ float quadf(float v) {
    return __builtin_bit_cast(float,
        __builtin_amdgcn_update_dpp(0, __builtin_bit_cast(int, v),
                                    CTRL, 0xF, 0xF, true));
}
__device__ __forceinline__ float fast_tanh(float v) {
    const float e = __expf(-2.0f * fabsf(v));
    const float t = (1.0f - e) * __builtin_amdgcn_rcpf(1.0f + e);
    return copysignf(t, v);
}
__device__ __forceinline__ u64 coh_load64(const u64* p) {
    return __hip_atomic_load((u64*)p, __ATOMIC_RELAXED, __HIP_MEMORY_SCOPE_AGENT);
}
__device__ __forceinline__ unsigned coh_load32(const unsigned* p) {
    return __hip_atomic_load((unsigned*)p, __ATOMIC_RELAXED, __HIP_MEMORY_SCOPE_AGENT);
}
__device__ __forceinline__ void coh_store32(u32* p, u32 v) {
    __hip_atomic_store(p, v, __ATOMIC_RELAXED, __HIP_MEMORY_SCOPE_AGENT);
}
__device__ __forceinline__ int swz(int ks, int krow) {      // byte-bit 4..6 XOR
    return ((krow & 1) << 6) | ((ks & 1) << 5) | ((krow >> 1) << 4);
}

// ---- prep: split fp32 weights into frag-ordered bf16 planes (runs once) ----
extern "C" __global__ void __launch_bounds__(256)
lstm_prep(const float* __restrict__ W_gh, const float* __restrict__ W_ih,
          const float* __restrict__ W_fh, const float* __restrict__ W_oh,
          short* __restrict__ wsp)
{
    const int idx  = blockIdx.x * 256 + threadIdx.x;   // (cgwv*8+ks)*64+lane
    const int lane = idx & 63;
    const int ks   = (idx >> 6) & 7;
    const int cgwv = idx >> 9;
    const int cg   = cgwv >> 4;
    const int wv   = cgwv & 15;
    const int gate = lane & 3;
    const int hcol_g = cg * 64 + wv * 4 + ((lane & 15) >> 2);
    const int krow = lane >> 4;
    const float* __restrict__ Wg =
        (gate == 0) ? W_gh : (gate == 1) ? W_ih : (gate == 2) ? W_fh : W_oh;
    s16x8 v1, v2;
    #pragma unroll
    for (int e = 0; e < 8; ++e) {
        const float w = Wg[(size_t)(ks * 32 + krow * 8 + e) * Hh + hcol_g];
        const unsigned short c1 = f2bf(w);
        const unsigned short c2 = f2bf(w - bf2f(c1));
        v1[e] = (short)c1; v2[e] = (short)c2;
    }
    *(s16x8*)(wsp + (size_t)idx * 8)              = v1;
    *(s16x8*)(wsp + (size_t)(WSPN + idx) * 8)     = v2;
}

extern "C" __global__ __attribute__((amdgpu_waves_per_eu(4, 4))) void
__launch_bounds__(NTHR)
lstm_v13(const float* __restrict__ x,
         const float* __restrict__ W_gx, const float* __restrict__ b_g,
         const float* __restrict__ W_ix, const float* __restrict__ b_i,
         const float* __restrict__ W_fx, const float* __restrict__ b_f,
         const float* __restrict__ W_ox, const float* __restrict__ b_o,
         const float* __restrict__ W_ph, const float* __restrict__ b_p,
         const short* __restrict__ wsp,
         float* __restrict__ out, u32* __restrict__ hpack, unsigned* __restrict__ fcnt)
{
    __shared__ __align__(16) char smem[SMEMB];
    u32* hown = (u32*)(smem + HOWNB);

    const int tid  = threadIdx.x;
    const int lane = tid & 63;
    const int wv   = tid >> 6;            // 0..15
    const int rg   = blockIdx.x & 63;
    const int cg   = blockIdx.x >> 6;     // 0..3
    const int r0   = rg * RGR;

    const int gate   = lane & 3;
    const int hcol_l = wv * 4 + ((lane & 15) >> 2);    // 0..63
    const int hcol_g = cg * 64 + hcol_l;
    const int krow   = lane >> 4;                      // 0..3

    // ---- pre-split weights: 16 coalesced dwordx4 frags, no VALU ----
    const s16x8* __restrict__ W1 =
        (const s16x8*)wsp + ((size_t)(cg * 16 + wv) * 8 * 64 + lane);
    const s16x8* __restrict__ W2 = W1 + WSPN;
    s16x8 bw1[8], bw2[8];
    #pragma unroll
    for (int ks = 0; ks < 8; ++ks) {
        bw1[ks] = W1[ks * 64];
        bw2[ks] = W2[ks * 64];
    }

    // reference bias swap preserved: f-gate uses b_o, o-gate uses b_f
    const float wx = ((gate == 0) ? W_gx : (gate == 1) ? W_ix : (gate == 2) ? W_fx : W_ox)[hcol_g];
    const float bb = ((gate == 0) ? b_g  : (gate == 1) ? b_i  : (gate == 2) ? b_o  : b_f )[hcol_g];
    float c_st[4];
    #pragma unroll
    for (int r = 0; r < 4; ++r) c_st[r] = 0.0f;

    // ---- staging role: slice s (a colgroup), quarter q (4 rows) ----
    const int s    = wv & 3;
    const int q    = wv >> 2;
    const int srow = q * 4 + krow;                 // 0..15
    const int sc4  = (lane & 15) * 4;              // u32 col in 64-col slice
    const int kg   = s * 64 + sc4;                 // global k of v[0]
    const int sks  = kg >> 5;
    const int skr  = (kg >> 3) & 3;
    const int se0  = kg & 7;                       // 0 or 4
    const int swb  = (sks * 1024 + (skr * 16 + srow) * 16 + se0 * 2) ^ swz(sks, skr);

    unsigned* fbase = fcnt + rg * NCG;

    for (int i = tid; i < 16 * HSTR; i += NTHR) hown[i] = 0u;
    __syncthreads();

    for (int t = 0; t < Tt; ++t) {
        const u32* hcur = hpack + ((t & 1) ? HSZ : 0);
        u32*       hnxt = hpack + ((t & 1) ? 0 : HSZ);

        // x_t for phase-B rows (early, cached broadcast)
        float xv[4];
        #pragma unroll
        for (int r = 0; r < 4; ++r)
            xv[r] = x[(size_t)(r0 + krow * 4 + r) * Tt + t];

        // ---- stage slice s: 4 u32 per lane ----
        u32 v0, v1, v2, v3;
        if (s != cg) {
            if (t > 0)
                while (coh_load32(fbase + s) < (unsigned)t) __builtin_amdgcn_s_sleep(1);
            const u64* src = (const u64*)(hcur + (size_t)(r0 + srow) * Hh + s * 64 + sc4);
            const u64 q0 = coh_load64(src);
            const u64 q1 = coh_load64(src + 1);
            v0 = (u32)q0; v1 = (u32)(q0 >> 32);
            v2 = (u32)q1; v3 = (u32)(q1 >> 32);
        } else {
            const uint4 qq = *(const uint4*)(hown + srow * HSTR + sc4);
            v0 = qq.x; v1 = qq.y; v2 = qq.z; v3 = qq.w;
        }
        {
            u32x2 lo, hi;
            lo[0] = (v0 & 0xffffu) | (v1 << 16);
            lo[1] = (v2 & 0xffffu) | (v3 << 16);
            hi[0] = (v0 >> 16) | (v1 & 0xffff0000u);
            hi[1] = (v2 >> 16) | (v3 & 0xffff0000u);
            *(u32x2*)(smem + PL1 + swb) = lo;
            *(u32x2*)(smem + PL2 + swb) = hi;
        }
        __syncthreads();                           // planes = split(h(t))

        // ---- MFMA: 8 ksteps x 3 terms, 3 independent chains ----
        f32x4 aA = {0.f,0.f,0.f,0.f}, aB = {0.f,0.f,0.f,0.f}, aC = {0.f,0.f,0.f,0.f};
        #pragma unroll
        for (int ks = 0; ks < 8; ++ks) {
            const int off = (ks * 1024 + lane * 16) ^ swz(ks, krow);
            const s16x8 a1 = *(const s16x8*)(smem + PL1 + off);
            const s16x8 a2 = *(const s16x8*)(smem + PL2 + off);
            aA = __builtin_amdgcn_mfma_f32_16x16x32_bf16(a1, bw1[ks], aA, 0, 0, 0);
            aB = __builtin_amdgcn_mfma_f32_16x16x32_bf16(a2, bw1[ks], aB, 0, 0, 0);
            aC = __builtin_amdgcn_mfma_f32_16x16x32_bf16(a1, bw2[ks], aC, 0, 0, 0);
        }
        const f32x4 acc = aA + aB + aC;

        // ---- phase B: 4 states/lane, in-register ----
        #pragma unroll
        for (int r = 0; r < 4; ++r) {
            const int row = krow * 4 + r;
            const float pre = acc[r] + fmaf(xv[r], wx, bb);
            const float vin = (gate == 0) ? 2.0f * pre : pre;
            const float e   = __expf(-fabsf(vin));
            const float rc  = __builtin_amdgcn_rcpf(1.0f + e);
            const float sig = (vin >= 0.0f) ? rc : 1.0f - rc;
            const float th  = copysignf((1.0f - e) * rc, pre);
            const float act = (gate == 0) ? th : sig;
            const float gv = quadf<0x00>(act);
            const float iv = quadf<0x55>(act);
            const float fv = quadf<0xAA>(act);
            const float ov = quadf<0xFF>(act);
            c_st[r] = fmaf(gv, iv, c_st[r] * fv);
            const float hv = fast_tanh(c_st[r]) * ov;
            if (gate == 0) {
                const unsigned short h1 = f2bf(hv);
                const unsigned short h2 = f2bf(hv - bf2f(h1));
                const u32 packed = (u32)h1 | ((u32)h2 << 16);
                coh_store32(&hnxt[(size_t)(r0 + row) * Hh + hcol_g], packed);
                hown[row * HSTR + hcol_l] = packed;
            }
        }

        asm volatile("s_waitcnt vmcnt(0)" ::: "memory");   // h stores at L3
        __syncthreads();                                    // all waves drained
        if (tid == 0)
            __hip_atomic_store(fbase + cg, (unsigned)(t + 1),
                               __ATOMIC_RELEASE, __HIP_MEMORY_SCOPE_AGENT);
    }

    // ---- classifier (cg==0): out = h_T @ W_ph + b_p (h_T in buffer 0) ----
    if (cg == 0) {
        for (int c = 1; c < NCG; ++c)
            while (coh_load32(fbase + c) < (unsigned)Tt) __builtin_amdgcn_s_sleep(1);
        u32* tile = (u32*)smem;                    // [16][256] packed h_T
        const u64* src = (const u64*)(hpack + (size_t)r0 * Hh);
        for (int i = tid; i < 16 * 128; i += NTHR) {
            const u64 qv = coh_load64(src + i);
            tile[2 * i] = (u32)qv; tile[2 * i + 1] = (u32)(qv >> 32);
        }
        __syncthreads();
        for (int idx = tid; idx < RGR * NCLS; idx += NTHR) {
            const int row = idx / NCLS;
            const int cc  = idx - row * NCLS;
            float a = b_p[cc];
            for (int k = 0; k < Hh; ++k) {
                const u32 p = tile[row * Hh + k];
                a = fmaf(bf2f((unsigned short)p) + bf2f((unsigned short)(p >> 16)),
                         W_ph[k * NCLS + cc], a);
            }
            out[(size_t)(r0 + row) * NCLS + cc] = a;
        }
    }
}

extern "C" void kernel_launch(void* const* d_in, const int* in_sizes, int n_in,
                              void* d_out, int out_size, void* d_ws, size_t ws_size,
                              hipStream_t stream) {
    const float* x    = (const float*)d_in[0];
    const float* W_gx = (const float*)d_in[1];
    const float* W_gh = (const float*)d_in[2];
    const float* b_g  = (const float*)d_in[3];
    const float* W_ix = (const float*)d_in[4];
    const float* W_ih = (const float*)d_in[5];
    const float* b_i  = (const float*)d_in[6];
    const float* W_fx = (const float*)d_in[7];
    const float* W_fh = (const float*)d_in[8];
    const float* b_f  = (const float*)d_in[9];
    const float* W_ox = (const float*)d_in[10];
    const float* W_oh = (const float*)d_in[11];
    const float* b_o  = (const float*)d_in[12];
    const float* W_ph = (const float*)d_in[13];
    const float* b_p  = (const float*)d_in[14];
    float* out = (float*)d_out;

    u32*      hpack = (u32*)d_ws;                            // 2 x 1 MB ping-pong
    unsigned* fcnt  = (unsigned*)((char*)d_ws + 2 * HSZ * sizeof(u32));
    short*    wsp   = (short*)((char*)d_ws + 2 * HSZ * sizeof(u32) + 4096);  // 1 MB
    const size_t clear_bytes = 2 * HSZ * sizeof(u32) + NRG * NCG * sizeof(unsigned);

    hipMemsetAsync(d_ws, 0, clear_bytes, stream);            // h0 = 0 + flags = 0

    lstm_prep<<<dim3(128), dim3(256), 0, stream>>>(W_gh, W_ih, W_fh, W_oh, wsp);

    lstm_v13<<<dim3(NRG * NCG), dim3(NTHR), 0, stream>>>(
        x, W_gx, b_g, W_ix, b_i, W_fx, b_f, W_ox, b_o,
        W_ph, b_p, wsp, out, hpack, fcnt);
}